// Round 1
// baseline (711.124 us; speedup 1.0000x reference)
//
#include <hip/hip_runtime.h>
#include <math.h>

// SfmPool: softmax-weighted 3x3 stride-2 SAME pooling, NHWC f32.
// Input  (32,128,128,192) -> Output (32,64,64,192).
//
// Reference math:
//   max_v[i,j] = sum over stride-2 3x3 windows covering (i,j) of window max
//   out[w] = sum_{e in w} v_e * exp(v_e - max_v_e) / sum_{e in w} exp(v_e - max_v_e)
// SAME padding: pad_lo=0, pad_hi=1; window (oh,ow) covers rows 2oh..2oh+2.

#define B  32
#define H  128
#define W  128
#define C  192
#define OH 64
#define OW 64

// Compile-time coverage: window (oh-1+a) covers input row (2*oh+di) iff
// a==1, or (a==0 && di==0), or (a==2 && di==2).
__device__ __forceinline__ constexpr bool cov(int d, int a) {
    return (a == 1) || (a == 0 && d == 0) || (a == 2 && d == 2);
}

__global__ __launch_bounds__(256) void sfmpool_kernel(
    const float* __restrict__ in, float* __restrict__ out, int total) {
    int n = blockIdx.x * blockDim.x + threadIdx.x;
    if (n >= total) return;

    int c  = n % C;
    int t  = n / C;
    int ow = t & 63;  t >>= 6;
    int oh = t & 63;
    int b  = t >> 6;

    const int i0 = 2 * oh - 2;   // top row of 7x7 neighborhood
    const int j0 = 2 * ow - 2;   // left col
    const float* base = in + ((size_t)b * H * W) * C + c;

    float rowmax[7][3];   // per neighborhood row, max over window-col q
    float center[3][3];   // the 3x3 input window of (oh,ow)

#pragma unroll
    for (int r = 0; r < 7; ++r) {
        int i = i0 + r;
        bool iok = (unsigned)i < (unsigned)H;   // wave-uniform
        float v[7];
#pragma unroll
        for (int s = 0; s < 7; ++s) {
            int j = j0 + s;
            bool ok = iok && ((unsigned)j < (unsigned)W);
            v[s] = ok ? base[((size_t)i * W + j) * C] : -INFINITY;
        }
#pragma unroll
        for (int q = 0; q < 3; ++q)
            rowmax[r][q] = fmaxf(fmaxf(v[2 * q], v[2 * q + 1]), v[2 * q + 2]);
        if (r >= 2 && r <= 4) {
#pragma unroll
            for (int dj = 0; dj < 3; ++dj)
                center[r - 2][dj] = v[2 + dj];
        }
    }

    // M[a][q] = max of window (oh-1+a, ow-1+q); window a uses rows 2a..2a+2.
    float M[3][3];
#pragma unroll
    for (int a = 0; a < 3; ++a)
#pragma unroll
        for (int q = 0; q < 3; ++q)
            M[a][q] = fmaxf(fmaxf(rowmax[2 * a][q], rowmax[2 * a + 1][q]),
                            rowmax[2 * a + 2][q]);

    float num = 0.f, den = 0.f;
#pragma unroll
    for (int di = 0; di < 3; ++di) {
        int i = 2 * oh + di;
        if (i >= H) continue;                   // padded row (oh==63, di==2)
#pragma unroll
        for (int dj = 0; dj < 3; ++dj) {
            int j = 2 * ow + dj;
            if (j >= W) continue;               // padded col
            float v = center[di][dj];
            float mv = 0.f;
#pragma unroll
            for (int a = 0; a < 3; ++a) {
                if (!cov(di, a)) continue;                       // compile-time
                if ((unsigned)(oh - 1 + a) >= (unsigned)OH) continue;  // wave-uniform
#pragma unroll
                for (int q = 0; q < 3; ++q) {
                    if (!cov(dj, q)) continue;                   // compile-time
                    if ((unsigned)(ow - 1 + q) >= (unsigned)OW) continue;
                    mv += M[a][q];
                }
            }
            float e = __expf(v - mv);
            num = fmaf(v, e, num);
            den += e;
        }
    }
    out[n] = num / den;
}

extern "C" void kernel_launch(void* const* d_in, const int* in_sizes, int n_in,
                              void* d_out, int out_size, void* d_ws, size_t ws_size,
                              hipStream_t stream) {
    const float* in = (const float*)d_in[0];
    float* out = (float*)d_out;
    int total = B * OH * OW * C;   // 25,165,824 == out_size
    int block = 256;
    int grid = (total + block - 1) / block;
    sfmpool_kernel<<<grid, block, 0, stream>>>(in, out, total);
}

// Round 2
// 596.089 us; speedup vs baseline: 1.1930x; 1.1930x over previous
//
#include <hip/hip_runtime.h>
#include <math.h>

// SfmPool: softmax-weighted 3x3 stride-2 SAME pooling, NHWC f32.
// Input (32,128,128,192) -> Output (32,64,64,192).
//
// Rolling-row formulation: one thread per (b, oh, c), sweeping ow=0..63.
// Per iteration p we load 2 new input columns (2p+1, 2p+2), compute the
// per-column vertical 3-row maxes vm[a] once, roll the window max
// M_p[a] = max(vm(2p), vm(2p+1), vm(2p+2)), and emit output ow=p-1 using
// the carried M history {M_{p-2}, M_{p-1}, M_p} and carried center values.
// All boundary masks are wave-uniform (lanes differ only in channel c).

#define B  32
#define H  128
#define W  128
#define C  192
#define OH 64
#define OW 64
#define NEG_INF (-__builtin_inff())

__device__ __forceinline__ void vm3(const float v[7], float vm[3]) {
    vm[0] = fmaxf(fmaxf(v[0], v[1]), v[2]);   // rows of window oh-1
    vm[1] = fmaxf(fmaxf(v[2], v[3]), v[4]);   // rows of window oh
    vm[2] = fmaxf(fmaxf(v[4], v[5]), v[6]);   // rows of window oh+1
}

// Emit one output. Mm1/M0/Mp1 = window maxes of col-windows ow-1, ow, ow+1
// (indexed by row-window a). c0/c1/c2 = input values at cols 2ow..2ow+2,
// rows 2oh..2oh+2 (indexed by di). Masks are wave-uniform.
__device__ __forceinline__ void emit_out(
    float* __restrict__ op,
    const float Mm1[3], const float M0[3], const float Mp1[3],
    const float c0[3], const float c1[3], const float c2[3],
    bool walo, bool wahi, bool wqlo, bool wqhi) {
    // Masked window maxes Z[a][q] (invalid windows contribute 0 to mv sums).
    float Z00 = (walo && wqlo) ? Mm1[0] : 0.f;
    float Z01 = walo ? M0[0] : 0.f;
    float Z02 = (walo && wqhi) ? Mp1[0] : 0.f;
    float Z10 = wqlo ? Mm1[1] : 0.f;
    float Z11 = M0[1];
    float Z12 = wqhi ? Mp1[1] : 0.f;
    float Z20 = (wahi && wqlo) ? Mm1[2] : 0.f;
    float Z21 = wahi ? M0[2] : 0.f;
    float Z22 = (wahi && wqhi) ? Mp1[2] : 0.f;

    // Column-coverage partial sums: T0 = q in {0,1}, T2 = q in {1,2}.
    float T0a0 = Z00 + Z01, T0a1 = Z10 + Z11, T0a2 = Z20 + Z21;
    float T2a0 = Z01 + Z02, T2a1 = Z11 + Z12, T2a2 = Z21 + Z22;

    // mv(di,dj) = sum over covering windows. cov(0)={0,1}, cov(1)={1}, cov(2)={1,2}.
    float mv00 = T0a0 + T0a1;
    float mv01 = Z01 + Z11;
    float mv02 = T2a0 + T2a1;
    float mv10 = T0a1;
    float mv11 = Z11;
    float mv12 = T2a1;
    float mv20 = T0a1 + T0a2;
    float mv21 = Z11 + Z21;
    float mv22 = T2a1 + T2a2;

    float num = 0.f, den = 0.f;
    float v, e;
    v = c0[0]; e = __expf(v - mv00); num = fmaf(v, e, num); den += e;
    v = c1[0]; e = __expf(v - mv01); num = fmaf(v, e, num); den += e;
    v = c0[1]; e = __expf(v - mv10); num = fmaf(v, e, num); den += e;
    v = c1[1]; e = __expf(v - mv11); num = fmaf(v, e, num); den += e;
    if (wqhi) {   // col 2ow+2 is a real input column
        v = c2[0]; e = __expf(v - mv02); num = fmaf(v, e, num); den += e;
        v = c2[1]; e = __expf(v - mv12); num = fmaf(v, e, num); den += e;
    }
    if (wahi) {   // row 2oh+2 is a real input row
        v = c0[2]; e = __expf(v - mv20); num = fmaf(v, e, num); den += e;
        v = c1[2]; e = __expf(v - mv21); num = fmaf(v, e, num); den += e;
        if (wqhi) {
            v = c2[2]; e = __expf(v - mv22); num = fmaf(v, e, num); den += e;
        }
    }
    *op = __fdividef(num, den);
}

__global__ __launch_bounds__(256) void sfmpool_row_kernel(
    const float* __restrict__ in, float* __restrict__ out) {
    int n = blockIdx.x * blockDim.x + threadIdx.x;
    int c = n % C;
    int t = n / C;            // t = b*OH + oh
    int oh = t & (OH - 1);
    int b  = t >> 6;

    const bool walo = (oh > 0);
    const bool wahi = (oh < OH - 1);

    // 7 row pointers (rows 2oh-2 .. 2oh+4, clamped) + validity.
    const float* img = in + (size_t)b * (H * W * C);
    const float* rp[7];
    bool rv[7];
    const int i0 = 2 * oh - 2;
#pragma unroll
    for (int r = 0; r < 7; ++r) {
        int i = i0 + r;
        rv[r] = (unsigned)i < (unsigned)H;
        int ic = i < 0 ? 0 : (i > H - 1 ? H - 1 : i);
        rp[r] = img + (size_t)ic * (W * C) + c;
    }

    // ---- init: column 0 ----
    float vmP[3];                 // vm of col 2p (left col of window p)
    float cP2R[3], cP1L[3], cP1R[3];   // center rows of cols 2p-2, 2p-1, 2p
    float Mm2[3] = {0.f, 0.f, 0.f};    // M_{p-2}
    float Mm1[3] = {0.f, 0.f, 0.f};    // M_{p-1}
    {
        float v[7];
#pragma unroll
        for (int r = 0; r < 7; ++r) v[r] = rv[r] ? rp[r][0] : NEG_INF;
        vm3(v, vmP);
        cP1R[0] = v[2]; cP1R[1] = v[3]; cP1R[2] = v[4];
        cP2R[0] = cP2R[1] = cP2R[2] = 0.f;
        cP1L[0] = cP1L[1] = cP1L[2] = 0.f;
    }
#pragma unroll
    for (int r = 0; r < 7; ++r) rp[r] += C;   // now at col 1

    float* op = out + (size_t)t * (OW * C) + c;

    // ---- main loop: p = 0..62; cols 2p+1, 2p+2 are always in-bounds ----
    for (int p = 0; p < 63; ++p) {
        float vl[7], vr[7];
#pragma unroll
        for (int r = 0; r < 7; ++r) {
            float xl = rp[r][0];
            float xr = rp[r][C];
            vl[r] = rv[r] ? xl : NEG_INF;
            vr[r] = rv[r] ? xr : NEG_INF;
        }
        float vmL[3], vmR[3];
        vm3(vl, vmL);
        vm3(vr, vmR);
        float Mp[3];
#pragma unroll
        for (int a = 0; a < 3; ++a)
            Mp[a] = fmaxf(fmaxf(vmP[a], vmL[a]), vmR[a]);

        if (p > 0) {   // emit ow = p-1 (wqhi always true here: ow <= 61)
            emit_out(op, Mm2, Mm1, Mp, cP2R, cP1L, cP1R,
                     walo, wahi, /*wqlo=*/(p > 1), /*wqhi=*/true);
            op += C;
        }

        // shift state
#pragma unroll
        for (int a = 0; a < 3; ++a) {
            Mm2[a] = Mm1[a]; Mm1[a] = Mp[a]; vmP[a] = vmR[a];
        }
#pragma unroll
        for (int k = 0; k < 3; ++k) {
            cP2R[k] = cP1R[k];
            cP1L[k] = vl[2 + k];
            cP1R[k] = vr[2 + k];
        }
#pragma unroll
        for (int r = 0; r < 7; ++r) rp[r] += 2 * C;
    }

    // ---- epilogue p = 63: col 127 valid, col 128 is SAME padding ----
    {
        float vl[7];
#pragma unroll
        for (int r = 0; r < 7; ++r) {
            float xl = rp[r][0];
            vl[r] = rv[r] ? xl : NEG_INF;
        }
        float vmL[3];
        vm3(vl, vmL);
        float Mp[3];
#pragma unroll
        for (int a = 0; a < 3; ++a) Mp[a] = fmaxf(vmP[a], vmL[a]);

        // emit ow = 62
        emit_out(op, Mm2, Mm1, Mp, cP2R, cP1L, cP1R,
                 walo, wahi, /*wqlo=*/true, /*wqhi=*/true);
        op += C;

        // shift for final output
        float fc0[3], fc1[3], fc2[3];
#pragma unroll
        for (int k = 0; k < 3; ++k) {
            fc0[k] = cP1R[k];      // col 126
            fc1[k] = vl[2 + k];    // col 127
            fc2[k] = 0.f;          // col 128 (padding, masked)
        }
        // emit ow = 63: window 64 and col 128 masked via wqhi=false
        emit_out(op, Mm1, Mp, Mp, fc0, fc1, fc2,
                 walo, wahi, /*wqlo=*/true, /*wqhi=*/false);
    }
}

extern "C" void kernel_launch(void* const* d_in, const int* in_sizes, int n_in,
                              void* d_out, int out_size, void* d_ws, size_t ws_size,
                              hipStream_t stream) {
    const float* in = (const float*)d_in[0];
    float* out = (float*)d_out;
    int total = B * OH * C;            // one thread per (b, oh, c)
    int block = 256;
    int grid = (total + block - 1) / block;   // 1536
    sfmpool_row_kernel<<<grid, block, 0, stream>>>(in, out);
}

// Round 3
// 558.939 us; speedup vs baseline: 1.2723x; 1.0665x over previous
//
#include <hip/hip_runtime.h>
#include <math.h>

// SfmPool: softmax-weighted 3x3 stride-2 SAME pooling, NHWC f32.
// Input (32,128,128,192) -> Output (32,64,64,192).
//
// Round 3: S=4 output rows per thread. Thread = (b, oh-group g of 4, ow-half, c).
// Sweeps 32 output cols; per step loads a 13-row x 2-col slab (26 dword loads,
// uniform-base + 32-bit byte offsets), computes per-column vertical maxes
// vm[w] for the 6 window-rows, rolls window maxes M_p[w], and emits 4 outputs
// (one per oh slot). M / center-value history kept in parity-indexed register
// rings; loop body 2x-unrolled so ring indices are compile-time (no shifts).
// Boundary oh-groups (g=0, g=15) and the two ow-halves are separate template
// instantiations -> interior path has no masks at all.

#define B  32
#define H  128
#define W  128
#define C  192
#define OH 64
#define OW 64
#define S  4
#define G  (OH / S)        // 16 oh-groups
#define NR (2 * S + 5)     // 13 strip rows
#define NW (S + 2)         // 6 window-rows
#define NCR (2 * S + 1)    // 9 center rows
#define CB (C * 4)         // 768 B per column step
#define OSTRIDE (OW * C * 4)  // 49152 B per output row
#define NEG_INF (-__builtin_inff())

// One output. Mm1/M0/Mp1: window maxes of col-windows ow-1, ow, ow+1 (a =
// window-row oh-1+a). c0/c1/c2: input cols 2ow..2ow+2, rows 2oh..2oh+2 (di).
// All masks are compile-time template bools.
template <bool WAL, bool WAH, bool WQL, bool WQH>
__device__ __forceinline__ float emit1(const float* Mm1, const float* M0,
                                       const float* Mp1, const float* c0,
                                       const float* c1, const float* c2) {
    const float Z00 = (WAL && WQL) ? Mm1[0] : 0.f;
    const float Z01 = WAL ? M0[0] : 0.f;
    const float Z02 = (WAL && WQH) ? Mp1[0] : 0.f;
    const float Z10 = WQL ? Mm1[1] : 0.f;
    const float Z11 = M0[1];
    const float Z12 = WQH ? Mp1[1] : 0.f;
    const float Z20 = (WAH && WQL) ? Mm1[2] : 0.f;
    const float Z21 = WAH ? M0[2] : 0.f;
    const float Z22 = (WAH && WQH) ? Mp1[2] : 0.f;

    const float T0a0 = Z00 + Z01, T0a1 = Z10 + Z11, T0a2 = Z20 + Z21;
    const float T2a0 = Z01 + Z02, T2a1 = Z11 + Z12, T2a2 = Z21 + Z22;

    const float mv00 = T0a0 + T0a1;
    const float mv01 = Z01 + Z11;
    const float mv02 = T2a0 + T2a1;
    const float mv10 = T0a1;
    const float mv11 = Z11;
    const float mv12 = T2a1;
    const float mv20 = T0a1 + T0a2;
    const float mv21 = Z11 + Z21;
    const float mv22 = T2a1 + T2a2;

    float num = 0.f, den = 0.f, v, e;
    v = c0[0]; e = __expf(v - mv00); num = fmaf(v, e, num); den += e;
    v = c1[0]; e = __expf(v - mv01); num = fmaf(v, e, num); den += e;
    v = c0[1]; e = __expf(v - mv10); num = fmaf(v, e, num); den += e;
    v = c1[1]; e = __expf(v - mv11); num = fmaf(v, e, num); den += e;
    if (WQH) {
        v = c2[0]; e = __expf(v - mv02); num = fmaf(v, e, num); den += e;
        v = c2[1]; e = __expf(v - mv12); num = fmaf(v, e, num); den += e;
    }
    if (WAH) {
        v = c0[2]; e = __expf(v - mv20); num = fmaf(v, e, num); den += e;
        v = c1[2]; e = __expf(v - mv21); num = fmaf(v, e, num); den += e;
        if (WQH) {
            v = c2[2]; e = __expf(v - mv22); num = fmaf(v, e, num); den += e;
        }
    }
    return __fdividef(num, den);
}

// One sweep step (iteration p): load cols 2p+1 (vl), 2p+2 (vr); emit ow=p-1.
// PAR = p&1 selects ring slots (compile-time).
template <int PAR, int RLO, int RHI, bool WALO, bool WAHI, bool LOADVL,
          bool LOADVR, bool EMIT, bool WQL, bool WQH>
__device__ __forceinline__ void step(const char* __restrict__ sb,
                                     unsigned off[NR], float vmP[NW],
                                     float Mh[2][NW], float CL[2][NCR],
                                     float CR[2][NCR], char* __restrict__ ob,
                                     unsigned& ooff) {
    float vl[NR], vr[NR];
#pragma unroll
    for (int r = 0; r < NR; ++r) {
        const bool rv = (r >= RLO && r <= RHI);
        vl[r] = (LOADVL && rv) ? *(const float*)(sb + off[r]) : NEG_INF;
        vr[r] = (LOADVR && rv) ? *(const float*)(sb + off[r] + CB) : NEG_INF;
    }
    float vmL[NW], vmR[NW], Mp[NW];
#pragma unroll
    for (int w = 0; w < NW; ++w) {
        vmL[w] = fmaxf(fmaxf(vl[2 * w], vl[2 * w + 1]), vl[2 * w + 2]);
        vmR[w] = fmaxf(fmaxf(vr[2 * w], vr[2 * w + 1]), vr[2 * w + 2]);
        Mp[w] = fmaxf(fmaxf(vmP[w], vmL[w]), vmR[w]);
    }
    if (EMIT) {
        // slot s -> oh = oh0+s; window-rows w=s..s+2; center rows k=2s..2s+2.
        {
            float o = emit1<WALO, true, WQL, WQH>(
                &Mh[PAR][0], &Mh[PAR ^ 1][0], &Mp[0],
                &CR[PAR][0], &CL[PAR ^ 1][0], &CR[PAR ^ 1][0]);
            *(float*)(ob + ooff + 0 * OSTRIDE) = o;
        }
        {
            float o = emit1<true, true, WQL, WQH>(
                &Mh[PAR][1], &Mh[PAR ^ 1][1], &Mp[1],
                &CR[PAR][2], &CL[PAR ^ 1][2], &CR[PAR ^ 1][2]);
            *(float*)(ob + ooff + 1 * OSTRIDE) = o;
        }
        {
            float o = emit1<true, true, WQL, WQH>(
                &Mh[PAR][2], &Mh[PAR ^ 1][2], &Mp[2],
                &CR[PAR][4], &CL[PAR ^ 1][4], &CR[PAR ^ 1][4]);
            *(float*)(ob + ooff + 2 * OSTRIDE) = o;
        }
        {
            float o = emit1<true, WAHI, WQL, WQH>(
                &Mh[PAR][3], &Mh[PAR ^ 1][3], &Mp[3],
                &CR[PAR][6], &CL[PAR ^ 1][6], &CR[PAR ^ 1][6]);
            *(float*)(ob + ooff + 3 * OSTRIDE) = o;
        }
        ooff += CB;
    }
    // ring update (after emit)
#pragma unroll
    for (int w = 0; w < NW; ++w) {
        Mh[PAR][w] = Mp[w];
        vmP[w] = vmR[w];
    }
#pragma unroll
    for (int k = 0; k < NCR; ++k) {
        CL[PAR][k] = vl[k + 2];
        CR[PAR][k] = vr[k + 2];
    }
    if (LOADVL) {
#pragma unroll
        for (int r = 0; r < NR; ++r)
            if (r >= RLO && r <= RHI) off[r] += 2 * CB;
    }
}

template <int RLO, int RHI, bool WALO, bool WAHI, bool FIRST>
__device__ __forceinline__ void sweep(const char* __restrict__ sb,
                                      char* __restrict__ ob, int oh0, int c) {
    constexpr int start = FIRST ? 0 : OW / 2;
    const int j0 = FIRST ? 0 : (2 * start - 2);  // first loaded column

    unsigned off[NR];
#pragma unroll
    for (int r = 0; r < NR; ++r) {
        int i = 2 * oh0 - 2 + r;
        if (i < 0) i = 0;
        if (i > H - 1) i = H - 1;
        off[r] = (unsigned)(((i * W + j0) * C + c) * 4);
    }

    float vmP[NW], Mh[2][NW], CL[2][NCR], CR[2][NCR];
    unsigned ooff = (unsigned)(((oh0 * OW + start) * C + c) * 4);

    // ---- warm-up ----
    float v0[NR];
#pragma unroll
    for (int r = 0; r < NR; ++r)
        v0[r] = (r >= RLO && r <= RHI) ? *(const float*)(sb + off[r]) : NEG_INF;

    if (FIRST) {
        // acts as iter p=-1 (PAR=1): vl(col -1) skipped, vr = col 0.
#pragma unroll
        for (int w = 0; w < NW; ++w) {
            float vm0 = fmaxf(fmaxf(v0[2 * w], v0[2 * w + 1]), v0[2 * w + 2]);
            Mh[1][w] = vm0;   // M_{-1} (consumed only under WQL=false mask)
            vmP[w] = vm0;     // vm of col 0
        }
#pragma unroll
        for (int k = 0; k < NCR; ++k) {
            CL[1][k] = NEG_INF;       // col -1, never consumed
            CR[1][k] = v0[k + 2];     // col 0 centers
        }
    } else {
        // pre-warm: col 62 -> vmP
#pragma unroll
        for (int w = 0; w < NW; ++w)
            vmP[w] = fmaxf(fmaxf(v0[2 * w], v0[2 * w + 1]), v0[2 * w + 2]);
    }
#pragma unroll
    for (int r = 0; r < NR; ++r)
        if (r >= RLO && r <= RHI) off[r] += CB;

    if (!FIRST) {
        // warm iter p=31 (PAR=1): cols 63,64
        step<1, RLO, RHI, WALO, WAHI, true, true, false, true, true>(
            sb, off, vmP, Mh, CL, CR, ob, ooff);
    }
    // warm iter p=start (PAR=0): cols 2*start+1, 2*start+2
    step<0, RLO, RHI, WALO, WAHI, true, true, false, true, true>(
        sb, off, vmP, Mh, CL, CR, ob, ooff);

    if (FIRST) {
        // peel p=1: emit ow=0 (left col-window masked)
        step<1, RLO, RHI, WALO, WAHI, true, true, true, false, true>(
            sb, off, vmP, Mh, CL, CR, ob, ooff);
#pragma unroll 1
        for (int t = 0; t < 15; ++t) {  // p = 2..31
            step<0, RLO, RHI, WALO, WAHI, true, true, true, true, true>(
                sb, off, vmP, Mh, CL, CR, ob, ooff);
            step<1, RLO, RHI, WALO, WAHI, true, true, true, true, true>(
                sb, off, vmP, Mh, CL, CR, ob, ooff);
        }
        // p=32: emit ow=31
        step<0, RLO, RHI, WALO, WAHI, true, true, true, true, true>(
            sb, off, vmP, Mh, CL, CR, ob, ooff);
    } else {
#pragma unroll 1
        for (int t = 0; t < 15; ++t) {  // p = 33..62
            step<1, RLO, RHI, WALO, WAHI, true, true, true, true, true>(
                sb, off, vmP, Mh, CL, CR, ob, ooff);
            step<0, RLO, RHI, WALO, WAHI, true, true, true, true, true>(
                sb, off, vmP, Mh, CL, CR, ob, ooff);
        }
        // p=63: vl = col 127, vr (col 128) padded; emit ow=62
        step<1, RLO, RHI, WALO, WAHI, true, false, true, true, true>(
            sb, off, vmP, Mh, CL, CR, ob, ooff);
        // p=64: emit-only, ow=63 (right col-window masked)
        step<0, RLO, RHI, WALO, WAHI, false, false, true, true, false>(
            sb, off, vmP, Mh, CL, CR, ob, ooff);
    }
}

__global__ __launch_bounds__(192, 3) void sfmpool_s4_kernel(
    const float* __restrict__ in, float* __restrict__ out) {
    const int c = threadIdx.x;            // 0..191 (channel)
    const int half = blockIdx.x;          // 0..1 (ow half)
    const int g = blockIdx.y;             // 0..15 (oh group)
    const int b = blockIdx.z;             // 0..31
    const char* sb = (const char*)(in + (size_t)b * (H * W * C));
    char* ob = (char*)(out + (size_t)b * (OH * OW * C));
    const int oh0 = g * S;

    if (g == 0) {
        if (half == 0) sweep<2, 12, false, true, true>(sb, ob, oh0, c);
        else           sweep<2, 12, false, true, false>(sb, ob, oh0, c);
    } else if (g == G - 1) {
        if (half == 0) sweep<0, 9, true, false, true>(sb, ob, oh0, c);
        else           sweep<0, 9, true, false, false>(sb, ob, oh0, c);
    } else {
        if (half == 0) sweep<0, 12, true, true, true>(sb, ob, oh0, c);
        else           sweep<0, 12, true, true, false>(sb, ob, oh0, c);
    }
}

extern "C" void kernel_launch(void* const* d_in, const int* in_sizes, int n_in,
                              void* d_out, int out_size, void* d_ws, size_t ws_size,
                              hipStream_t stream) {
    const float* in = (const float*)d_in[0];
    float* out = (float*)d_out;
    dim3 grid(2, G, B);   // (ow-half, oh-group, batch) = 1024 blocks
    dim3 block(C);        // 192 threads = 3 waves (lane = channel)
    sfmpool_s4_kernel<<<grid, block, 0, stream>>>(in, out);
}